// Round 9
// baseline (325.921 us; speedup 1.0000x reference)
//
#include <hip/hip_runtime.h>
#include <hip/hip_bf16.h>
#include <math.h>

// Problem constants (fixed by the reference).
#define BB    4
#define CC    256
#define CHN   128
#define NN    4096

typedef short short8 __attribute__((ext_vector_type(8)));    // 8 bf16 (MFMA A/B frag)
typedef float f32x4  __attribute__((ext_vector_type(4)));    // 16x16 C/D frag
typedef float f32x16 __attribute__((ext_vector_type(16)));   // 32x32 C/D frag
typedef unsigned short u16;
typedef u16  us4 __attribute__((ext_vector_type(4)));

#define MFMA16(a, b, c) __builtin_amdgcn_mfma_f32_16x16x32_bf16((a), (b), (c), 0, 0, 0)
#define MFMA32(a, b, c) __builtin_amdgcn_mfma_f32_32x32x16_bf16((a), (b), (c), 0, 0, 0)
#define LOG2E 1.4426950408889634f

#if __has_builtin(__builtin_amdgcn_exp2f)
#define EXP2F(x) __builtin_amdgcn_exp2f(x)
#else
#define EXP2F(x) exp2f(x)
#endif
#if __has_builtin(__builtin_amdgcn_logf)
#define LOG2F(x) __builtin_amdgcn_logf(x)   // v_log_f32 IS log2
#else
#define LOG2F(x) log2f(x)
#endif

static __device__ __forceinline__ u16 f2bf(float f) {           // RNE float->bf16
    union { float f; unsigned u; } v; v.f = f;
    unsigned r = v.u + 0x7FFFu + ((v.u >> 16) & 1u);
    return (u16)(r >> 16);
}
// packed f32x2 -> bf16x2 (v_cvt_pk_bf16_f32 on gfx950)
static __device__ __forceinline__ unsigned pkbf(float a, float b) {
    __hip_bfloat162 h = __float22bfloat162_rn(make_float2(a, b));
    return *reinterpret_cast<unsigned*>(&h);
}
// XOR-swizzled LDS address (u16 units), [row][128] bf16 tiles, 16B chunks.
static __device__ __forceinline__ int sw128(int row, int u) {
    return row * 128 + ((u ^ (row & 7)) << 3);
}

typedef union { unsigned u[4]; short8 v; } bfrag;

// E = exp2(sv) -> packed bf16 PV B-operand frags.
// Half-exchange via v_permlane32_swap (VALU, validated R2) instead of
// ds_bpermute: swap(e0,e2) -> res0 = f[0].u[0], res1 = f[0].u[2].
#if __has_builtin(__builtin_amdgcn_permlane32_swap)
#define REPACK(sv, f) do { \
    unsigned e0 = pkbf(EXP2F(sv[0]),  EXP2F(sv[1])); \
    unsigned e1 = pkbf(EXP2F(sv[2]),  EXP2F(sv[3])); \
    unsigned e2 = pkbf(EXP2F(sv[4]),  EXP2F(sv[5])); \
    unsigned e3 = pkbf(EXP2F(sv[6]),  EXP2F(sv[7])); \
    unsigned e4 = pkbf(EXP2F(sv[8]),  EXP2F(sv[9])); \
    unsigned e5 = pkbf(EXP2F(sv[10]), EXP2F(sv[11])); \
    unsigned e6 = pkbf(EXP2F(sv[12]), EXP2F(sv[13])); \
    unsigned e7 = pkbf(EXP2F(sv[14]), EXP2F(sv[15])); \
    auto r02 = __builtin_amdgcn_permlane32_swap(e0, e2, false, false); \
    auto r13 = __builtin_amdgcn_permlane32_swap(e1, e3, false, false); \
    auto r46 = __builtin_amdgcn_permlane32_swap(e4, e6, false, false); \
    auto r57 = __builtin_amdgcn_permlane32_swap(e5, e7, false, false); \
    f[0].u[0] = r02[0]; f[0].u[1] = r13[0]; \
    f[0].u[2] = r02[1]; f[0].u[3] = r13[1]; \
    f[1].u[0] = r46[0]; f[1].u[1] = r57[0]; \
    f[1].u[2] = r46[1]; f[1].u[3] = r57[1]; \
} while (0)
#else
// validated fallback (shfl_xor / ds_bpermute path)
#define REPACK(sv, f) do { \
    unsigned e0 = pkbf(EXP2F(sv[0]),  EXP2F(sv[1])); \
    unsigned e1 = pkbf(EXP2F(sv[2]),  EXP2F(sv[3])); \
    unsigned e2 = pkbf(EXP2F(sv[4]),  EXP2F(sv[5])); \
    unsigned e3 = pkbf(EXP2F(sv[6]),  EXP2F(sv[7])); \
    unsigned e4 = pkbf(EXP2F(sv[8]),  EXP2F(sv[9])); \
    unsigned e5 = pkbf(EXP2F(sv[10]), EXP2F(sv[11])); \
    unsigned e6 = pkbf(EXP2F(sv[12]), EXP2F(sv[13])); \
    unsigned e7 = pkbf(EXP2F(sv[14]), EXP2F(sv[15])); \
    unsigned q0 = __shfl_xor(e0, 32), q1 = __shfl_xor(e1, 32); \
    unsigned q2 = __shfl_xor(e2, 32), q3 = __shfl_xor(e3, 32); \
    unsigned q4 = __shfl_xor(e4, 32), q5 = __shfl_xor(e5, 32); \
    unsigned q6 = __shfl_xor(e6, 32), q7 = __shfl_xor(e7, 32); \
    f[0].u[0] = lh ? q2 : e0;  f[0].u[1] = lh ? q3 : e1; \
    f[0].u[2] = lh ? e2 : q0;  f[0].u[3] = lh ? e3 : q1; \
    f[1].u[0] = lh ? q6 : e4;  f[1].u[1] = lh ? q7 : e5; \
    f[1].u[2] = lh ? e6 : q4;  f[1].u[3] = lh ? e7 : q5; \
} while (0)
#endif

// ---------------------------------------------------------------------------
// K0: convert 4 weight matrices fp32->bf16. wall = [tw|pw|gw|Ww], 32768 each.
// theta weights pre-scaled by log2(e): scores land in exp2 domain.
// ---------------------------------------------------------------------------
__global__ __launch_bounds__(256) void k_cvtw(
    const float* __restrict__ tw, const float* __restrict__ pw,
    const float* __restrict__ gw, const float* __restrict__ Ww,
    u16* __restrict__ wall)
{
    int idx = (blockIdx.x * 256 + threadIdx.x) * 4;   // 0 .. 131071
    const float* s = (idx < 32768) ? tw
                   : (idx < 65536) ? pw
                   : (idx < 98304) ? gw : Ww;
    float sc = (idx < 32768) ? LOG2E : 1.0f;
    float4 v = *(const float4*)(s + (idx & 32767));
    us4 r = { f2bf(v.x * sc), f2bf(v.y * sc), f2bf(v.z * sc), f2bf(v.w * sc) };
    *(us4*)(wall + idx) = r;
}

// ---------------------------------------------------------------------------
// K1: MFMA projections (16x16 path, unchanged — validated).
//  tht/pht: [b][n][c] bf16 k-major; gg: [b][c][n] bf16 (k-major in j).
// ---------------------------------------------------------------------------
__global__ __launch_bounds__(512) void k_proj(
    const float* __restrict__ x, const u16* __restrict__ wall,
    const float* __restrict__ tb, const float* __restrict__ pb,
    const float* __restrict__ gbias,
    u16* __restrict__ tht, u16* __restrict__ pht, u16* __restrict__ gg)
{
    __shared__ u16 xs[64 * 264];    // x^T tile [n][c], pitch 264
    __shared__ u16 gbuf[128 * 68];  // g transpose bounce [o][n]
    const int tid = threadIdx.x;
    const int n0  = blockIdx.x * 64;
    const int b   = blockIdx.y;
    const int ln  = tid & 15, q = (tid >> 4) & 3, wid = tid >> 6;
    const int ow  = wid & 1, nw = wid >> 1;

    for (int p = 0; p < 8; ++p) {
        int id = p * 512 + tid;          // 4096 chunks: c(256) x n4(16)
        int c = id >> 4, n4 = (id & 15) * 4;
        float4 xv = *(const float4*)(x + ((size_t)b * CC + c) * NN + n0 + n4);
        xs[(n4 + 0) * 264 + c] = f2bf(xv.x);
        xs[(n4 + 1) * 264 + c] = f2bf(xv.y);
        xs[(n4 + 2) * 264 + c] = f2bf(xv.z);
        xs[(n4 + 3) * 264 + c] = f2bf(xv.w);
    }
    __syncthreads();

    short8 bfr[8];
    #pragma unroll
    for (int ks = 0; ks < 8; ++ks)
        bfr[ks] = *(const short8*)(&xs[(nw * 16 + ln) * 264 + ks * 32 + q * 8]);

    for (int pr = 0; pr < 3; ++pr) {
        const u16* wsrc = wall + pr * 32768;
        f32x4 acc[4];
        #pragma unroll
        for (int oo = 0; oo < 4; ++oo) acc[oo] = (f32x4){0.f, 0.f, 0.f, 0.f};
        for (int ks = 0; ks < 8; ++ks) {
            short8 a[4];
            #pragma unroll
            for (int oo = 0; oo < 4; ++oo)
                a[oo] = *(const short8*)(wsrc + (size_t)(ow*64 + oo*16 + ln) * 256 + ks*32 + q*8);
            #pragma unroll
            for (int oo = 0; oo < 4; ++oo)
                acc[oo] = MFMA16(a[oo], bfr[ks], acc[oo]);
        }
        const float* bias = (pr == 0) ? tb : (pr == 1 ? pb : gbias);
        const float bsc = (pr == 0) ? LOG2E : 1.0f;
        if (pr < 2) {
            u16* dst = (pr == 0) ? tht : pht;
            const int n = n0 + nw * 16 + ln;
            #pragma unroll
            for (int oo = 0; oo < 4; ++oo) {
                int o = ow * 64 + oo * 16 + q * 4;
                float4 bv = *(const float4*)(bias + o);
                f32x4 v = acc[oo];
                uint2 r = { pkbf(v.x + bv.x * bsc, v.y + bv.y * bsc),
                            pkbf(v.z + bv.z * bsc, v.w + bv.w * bsc) };
                *(uint2*)(dst + ((size_t)b * NN + n) * CHN + o) = r;
            }
        } else {
            const int nl = nw * 16 + ln;
            #pragma unroll
            for (int oo = 0; oo < 4; ++oo) {
                int o = ow * 64 + oo * 16 + q * 4;
                float4 bv = *(const float4*)(bias + o);
                f32x4 v = acc[oo];
                gbuf[(o + 0) * 68 + nl] = f2bf(v.x + bv.x);
                gbuf[(o + 1) * 68 + nl] = f2bf(v.y + bv.y);
                gbuf[(o + 2) * 68 + nl] = f2bf(v.z + bv.z);
                gbuf[(o + 3) * 68 + nl] = f2bf(v.w + bv.w);
            }
            __syncthreads();
            for (int p = 0; p < 4; ++p) {
                int id = p * 512 + tid;      // 2048 chunks: c(128) x n4(16)
                int c = id >> 4, n4 = (id & 15) * 4;
                us4 r = *(const us4*)(&gbuf[c * 68 + n4]);
                *(us4*)(gg + ((size_t)b * CHN + c) * NN + n0 + n4) = r;
            }
        }
    }
}

// ---------------------------------------------------------------------------
// K2 v2: partial Z[b][j] += sum_i exp2(S2_ji) — DIRECT-GLOBAL (no LDS, no
// barriers). The ph slab per (j-block, i-slab) is 256 KB, read identically
// by all waves -> L2/L3-resident (guide m169: staging cache-fit data is
// pure overhead). Per wave: ar[8] th-rows fixed; loop 32 i-tiles: 8 direct
// 16B loads + 8 MFMA + exp2-accumulate. Live regs ~115 (<=128 cap of
// (512,2) — validated headroom). Math order identical to R2 (bit-exact).
// ---------------------------------------------------------------------------
__global__ __launch_bounds__(512, 2) void k_rowsum(
    const u16* __restrict__ tht, const u16* __restrict__ pht,
    float* __restrict__ Z)
{
    const int tid = threadIdx.x;
    const int j0  = blockIdx.x * 256;
    const int i00 = blockIdx.y * 1024;
    const int b   = blockIdx.z;
    const int l   = tid & 63, w = tid >> 6;
    const int lm  = l & 31, lh = l >> 5;
    const u16* thb = tht + (size_t)b * NN * CHN;
    const u16* phb = pht + (size_t)b * NN * CHN;

    short8 ar[8];
    #pragma unroll
    for (int ks = 0; ks < 8; ++ks)
        ar[ks] = *(const short8*)(thb + (size_t)(j0 + w*32 + lm) * CHN + ks*16 + lh*8);

    float zp[16];
    #pragma unroll
    for (int r = 0; r < 16; ++r) zp[r] = 0.f;

    const u16* prow = phb + (size_t)(i00 + lm) * CHN + lh*8;
    for (int ii = 0; ii < 32; ++ii) {
        short8 bf[8];
        #pragma unroll
        for (int ks = 0; ks < 8; ++ks)
            bf[ks] = *(const short8*)(prow + (size_t)ii * 32 * CHN + ks*16);
        f32x16 s;
        #pragma unroll
        for (int r = 0; r < 16; ++r) s[r] = 0.f;
        __builtin_amdgcn_s_setprio(1);
        #pragma unroll
        for (int ks = 0; ks < 8; ++ks)
            s = MFMA32(ar[ks], bf[ks], s);
        __builtin_amdgcn_s_setprio(0);
        #pragma unroll
        for (int r = 0; r < 16; ++r) zp[r] += EXP2F(s[r]);
    }

    float zr[16];
    #pragma unroll
    for (int r = 0; r < 16; ++r) {
        float v = zp[r];
        v += __shfl_xor(v, 1);
        v += __shfl_xor(v, 2);
        v += __shfl_xor(v, 4);
        v += __shfl_xor(v, 8);
        v += __shfl_xor(v, 16);
        zr[r] = v;
    }
    if (lm == 0) {
        #pragma unroll
        for (int r = 0; r < 16; ++r) {
            int j = j0 + w*32 + (r & 3) + 8*(r >> 2) + 4*lh;
            atomicAdd(&Z[(size_t)b * NN + j], zr[r]);
        }
    }
}

// ---------------------------------------------------------------------------
// K2b: L[j] = -log2(Z[j])  (negated log-partition; k_attn C-init reads this)
// ---------------------------------------------------------------------------
__global__ __launch_bounds__(256) void k_log(
    const float* __restrict__ Z, float* __restrict__ L)
{
    int idx = (blockIdx.x * 256 + threadIdx.x) * 4;
    float4 z = *(const float4*)(Z + idx);
    float4 r = { -LOG2F(z.x), -LOG2F(z.y), -LOG2F(z.z), -LOG2F(z.w) };
    *(float4*)(L + idx) = r;
}

// ---------------------------------------------------------------------------
// K3 v9: fused attention — DIRECT-GLOBAL, BARRIER-FREE.
// Evidence chain: R2/R4/R8 showed the LDS-staging+barrier-per-step structure
// is the ceiling (dur tracks MFMA-per-barrier granularity: 64->50.7us,
// 32->51.6, 16->60.2; invariant to LDS-op count, block decoupling, TLP).
// The th/g/ph slabs per (jq,b) are 256 KB each, read identically by every
// wave -> L2/L3-resident (tht+pht+gg total 12 MB << 256 MB L3). So drop LDS
// entirely (guide m169 precedent: +26% dropping cache-fit staging):
//  - th A-frags + g A-frags loaded per-jj directly from global (16B/lane)
//  - phi in registers (unchanged); NO barriers, NO staging, NO bank
//    conflicts; every wave independent. Math order identical to R2.
//  - T5 setprio(1) around MFMA clusters (m191: +4-7% for independent-wave
//    attn — exactly this shape).
// Live regs ~165 peak (pacc 64 + phr 32 + a 32 + sv 16 + temps); plain
// __launch_bounds__(256) -> allocator default 180 (measured R6/R7) fits.
// Grid (32, 4, B) = 512 blocks x 4 waves = 2 blocks/CU (8 waves/CU at
// 180 VGPR = 2/SIMD). innerT: 4 j-slabs (validated R2 k_final).
// D-layout (m74/m101): col=lane&31, row=(r&3)+8*(r>>2)+4*(lane>>5).
// ---------------------------------------------------------------------------
__global__ __launch_bounds__(256) void k_attn(
    const u16* __restrict__ tht, const u16* __restrict__ pht,
    const u16* __restrict__ gg, const float* __restrict__ Lbuf,
    u16* __restrict__ innerT)
{
    const int tid = threadIdx.x;
    const int i0  = blockIdx.x * 128;    // 4 waves x i-32
    const int jq  = blockIdx.y;          // 0..3 -> j-1024 slab
    const int b   = blockIdx.z;
    const int w   = tid >> 6;
    const int lm  = tid & 31, lh = (tid >> 5) & 1;

    const u16*  thb = tht + (size_t)b * NN * CHN;
    const u16*  ggb = gg  + (size_t)b * CHN * NN;
    const float* Lb = Lbuf + (size_t)b * NN;

    // phi B-frags for this wave's i-32 (col n = lm), all K=128: registers.
    short8 phr[8];
    #pragma unroll
    for (int ks = 0; ks < 8; ++ks)
        phr[ks] = *(const short8*)(pht + ((size_t)b * NN + i0 + w*32 + lm) * CHN + ks*16 + lh*8);

    f32x16 pacc[4];   // [c-tile]: rows c, col i = lm (wave's i-32)
    #pragma unroll
    for (int ct = 0; ct < 4; ++ct)
        #pragma unroll
        for (int r = 0; r < 16; ++r) pacc[ct][r] = 0.f;

    // lane-fixed base pointers (compiler folds per-jj offsets to immediates)
    const u16* throw_ = thb + (size_t)(jq*1024 + lm) * CHN + lh*8;
    const u16* grow   = ggb + (size_t)lm * NN + jq*1024 + lh*8;

    for (int jj = 0; jj < 32; ++jj) {
        const int j0s = jq*1024 + jj*32;
        // --- th A-frags: direct 16B global loads (L2-hit; 8 independent)
        short8 a[8];
        #pragma unroll
        for (int ks = 0; ks < 8; ++ks)
            a[ks] = *(const short8*)(throw_ + (size_t)jj * 32 * CHN + ks*16);
        // --- S-tile: C-init = -log2 Z (precomputed), rows j, col i=lm
        f32x16 sv;
        #pragma unroll
        for (int rq = 0; rq < 4; ++rq) {
            float4 Lv = *(const float4*)(Lb + j0s + rq*8 + lh*4);
            sv[rq*4 + 0] = Lv.x; sv[rq*4 + 1] = Lv.y;
            sv[rq*4 + 2] = Lv.z; sv[rq*4 + 3] = Lv.w;
        }
        __builtin_amdgcn_s_setprio(1);
        #pragma unroll
        for (int ks = 0; ks < 8; ++ks)
            sv = MFMA32(a[ks], phr[ks], sv);
        __builtin_amdgcn_s_setprio(0);
        // --- E = exp2(sv) -> PV B-operand frags (permlane32_swap, VALU)
        bfrag f[2];
        REPACK(sv, f);
        // --- PV: pacc[c][i] += g[c][j] x E[j][i]; g frags direct from L2
        __builtin_amdgcn_s_setprio(1);
        #pragma unroll
        for (int h = 0; h < 2; ++h) {
            #pragma unroll
            for (int ct = 0; ct < 4; ++ct) {
                short8 ag = *(const short8*)(grow + (size_t)ct * 32 * NN + jj*32 + h*16);
                pacc[ct] = MFMA32(ag, f[h].v, pacc[ct]);
            }
        }
        __builtin_amdgcn_s_setprio(0);
    }

    // epilogue: D col = i (lane), rows = c -> 8B stores into innerT[i][c]
    u16* dst = innerT + ((size_t)jq * BB + b) * (size_t)NN * CHN;
    const int i = i0 + w*32 + lm;
    #pragma unroll
    for (int ct = 0; ct < 4; ++ct) {
        #pragma unroll
        for (int rq = 0; rq < 4; ++rq) {
            const int c0 = ct*32 + rq*8 + lh*4;
            uint2 r = { pkbf(pacc[ct][rq*4+0], pacc[ct][rq*4+1]),
                        pkbf(pacc[ct][rq*4+2], pacc[ct][rq*4+3]) };
            *(uint2*)(dst + (size_t)i * CHN + c0) = r;
        }
    }
}

// ---------------------------------------------------------------------------
// K4: out = Wb + x + Ww.(sum_q innerT_q) — 4 j-slabs, R2-exact (validated).
// ---------------------------------------------------------------------------
__global__ __launch_bounds__(512, 2) void k_final(
    const u16* __restrict__ innerT, const float* __restrict__ x,
    const u16* __restrict__ Wwbf, const float* __restrict__ Wb,
    float* __restrict__ out)
{
    __shared__ u16 w_s[256 * 128];   // 64 KB [o][c]
    __shared__ u16 a_s[64 * 128];    // 16 KB [n][c]
    const int tid = threadIdx.x;
    const int n0  = blockIdx.x * 64;
    const int b   = blockIdx.y;
    const int l   = tid & 63, w = tid >> 6;
    const int lm  = l & 31, lh = l >> 5;

    for (int p = 0; p < 8; ++p) {
        int id = p * 512 + tid;
        int row = id >> 4, u = id & 15;
        *(short8*)(&w_s[sw128(row, u)]) = *(const short8*)(Wwbf + (size_t)row * CHN + u * 8);
    }
    __syncthreads();

    short8 aw[8];
    #pragma unroll
    for (int ks = 0; ks < 8; ++ks)
        aw[ks] = *(const short8*)(&w_s[sw128(w*32 + lm, ks*2 + lh)]);

    f32x16 acc[2];
    #pragma unroll
    for (int nt = 0; nt < 2; ++nt)
        #pragma unroll
        for (int r = 0; r < 16; ++r) acc[nt][r] = 0.f;

    for (int jq = 0; jq < 4; ++jq) {
        __syncthreads();
        for (int p = 0; p < 2; ++p) {
            int id = p * 512 + tid;
            int row = id >> 4, u = id & 15;
            *(short8*)(&a_s[sw128(row, u)]) =
                *(const short8*)(innerT + (((size_t)jq * BB + b) * NN + n0 + row) * CHN + u * 8);
        }
        __syncthreads();
        #pragma unroll
        for (int ks = 0; ks < 8; ++ks) {
            short8 bn[2];
            #pragma unroll
            for (int nt = 0; nt < 2; ++nt)
                bn[nt] = *(const short8*)(&a_s[sw128(nt*32 + lm, ks*2 + lh)]);
            acc[0] = MFMA32(aw[ks], bn[0], acc[0]);
            acc[1] = MFMA32(aw[ks], bn[1], acc[1]);
        }
    }

    #pragma unroll
    for (int nt = 0; nt < 2; ++nt) {
        const int n = n0 + nt*32 + lm;
        #pragma unroll
        for (int r = 0; r < 16; ++r) {
            const int o = w*32 + (r & 3) + 8*(r >> 2) + 4*lh;
            const size_t idx = ((size_t)b * CC + o) * NN + n;
            out[idx] = acc[nt][r] + Wb[o] + x[idx];
        }
    }
}

// ---------------------------------------------------------------------------
extern "C" void kernel_launch(void* const* d_in, const int* in_sizes, int n_in,
                              void* d_out, int out_size, void* d_ws, size_t ws_size,
                              hipStream_t stream)
{
    const float* x  = (const float*)d_in[0];
    const float* tw = (const float*)d_in[1];
    const float* tb = (const float*)d_in[2];
    const float* pw = (const float*)d_in[3];
    const float* pb = (const float*)d_in[4];
    const float* gw = (const float*)d_in[5];
    const float* gb = (const float*)d_in[6];
    const float* Ww = (const float*)d_in[7];
    const float* Wb = (const float*)d_in[8];
    float* out = (float*)d_out;

    // Workspace (~29 MB): tht|pht|gg (4MB ea bf16) | wall (256KB) |
    // Z (64KB, memset 0) | L (64KB) | innerT 4 j-slabs x 4MB bf16.
    char* p = (char*)d_ws;
    const size_t proj_u16 = (size_t)BB * NN * CHN;   // 2,097,152
    u16*   tht    = (u16*)p;   p += proj_u16 * 2;
    u16*   pht    = (u16*)p;   p += proj_u16 * 2;
    u16*   gg     = (u16*)p;   p += proj_u16 * 2;
    u16*   wall   = (u16*)p;   p += (size_t)131072 * 2;
    float* Z      = (float*)p; p += (size_t)BB * NN * 4;
    float* Lbuf   = (float*)p; p += (size_t)BB * NN * 4;
    u16*   innerT = (u16*)p;

    hipMemsetAsync(Z, 0, (size_t)BB * NN * sizeof(float), stream);
    k_cvtw  <<<128, 256, 0, stream>>>(tw, pw, gw, Ww, wall);
    k_proj  <<<dim3(64, BB), 512, 0, stream>>>(x, wall, tb, pb, gb, tht, pht, gg);
    k_rowsum<<<dim3(16, 4, BB), 512, 0, stream>>>(tht, pht, Z);
    k_log   <<<16, 256, 0, stream>>>(Z, Lbuf);
    k_attn  <<<dim3(32, 4, BB), 256, 0, stream>>>(tht, pht, gg, Lbuf, innerT);
    k_final <<<dim3(64, BB), 512, 0, stream>>>(innerT, x, wall + 98304, Wb, out);
}

// Round 10
// 185.306 us; speedup vs baseline: 1.7588x; 1.7588x over previous
//
#include <hip/hip_runtime.h>
#include <hip/hip_bf16.h>
#include <math.h>

// Problem constants (fixed by the reference).
#define BB    4
#define CC    256
#define CHN   128
#define NN    4096

typedef short short8 __attribute__((ext_vector_type(8)));    // 8 bf16 (MFMA A/B frag)
typedef float f32x4  __attribute__((ext_vector_type(4)));    // 16x16 C/D frag
typedef float f32x16 __attribute__((ext_vector_type(16)));   // 32x32 C/D frag
typedef unsigned short u16;
typedef u16  us4 __attribute__((ext_vector_type(4)));

#define MFMA16(a, b, c) __builtin_amdgcn_mfma_f32_16x16x32_bf16((a), (b), (c), 0, 0, 0)
#define MFMA32(a, b, c) __builtin_amdgcn_mfma_f32_32x32x16_bf16((a), (b), (c), 0, 0, 0)
#define LOG2E 1.4426950408889634f

#if __has_builtin(__builtin_amdgcn_exp2f)
#define EXP2F(x) __builtin_amdgcn_exp2f(x)
#else
#define EXP2F(x) exp2f(x)
#endif
#if __has_builtin(__builtin_amdgcn_rcpf)
#define RCPF(x) __builtin_amdgcn_rcpf(x)
#else
#define RCPF(x) (1.0f / (x))
#endif

static __device__ __forceinline__ u16 f2bf(float f) {           // RNE float->bf16
    union { float f; unsigned u; } v; v.f = f;
    unsigned r = v.u + 0x7FFFu + ((v.u >> 16) & 1u);
    return (u16)(r >> 16);
}
static __device__ __forceinline__ float bf2f(u16 h) {
    union { unsigned u; float f; } v; v.u = ((unsigned)h) << 16;
    return v.f;
}
// packed f32x2 -> bf16x2 (v_cvt_pk_bf16_f32 on gfx950)
static __device__ __forceinline__ unsigned pkbf(float a, float b) {
    __hip_bfloat162 h = __float22bfloat162_rn(make_float2(a, b));
    return *reinterpret_cast<unsigned*>(&h);
}
// XOR-swizzled LDS address (u16 units), [row][128] bf16 tiles, 16B chunks.
static __device__ __forceinline__ int sw128(int row, int u) {
    return row * 128 + ((u ^ (row & 7)) << 3);
}
// async 16B global->LDS (linear dest: wave-uniform base + lane*16).
static __device__ __forceinline__ void gload16(const u16* g, u16* l) {
    __builtin_amdgcn_global_load_lds(
        (const __attribute__((address_space(1))) void*)g,
        (__attribute__((address_space(3))) void*)l, 16, 0, 0);
}

typedef union { unsigned u[4]; short8 v; } bfrag;

// E = exp2(sv) -> packed bf16 PV B-operand frags.
// Half-exchange via v_permlane32_swap (VALU, validated R2) instead of
// ds_bpermute: swap(e0,e2) -> res0 = f[0].u[0], res1 = f[0].u[2].
#if __has_builtin(__builtin_amdgcn_permlane32_swap)
#define REPACK(sv, f) do { \
    unsigned e0 = pkbf(EXP2F(sv[0]),  EXP2F(sv[1])); \
    unsigned e1 = pkbf(EXP2F(sv[2]),  EXP2F(sv[3])); \
    unsigned e2 = pkbf(EXP2F(sv[4]),  EXP2F(sv[5])); \
    unsigned e3 = pkbf(EXP2F(sv[6]),  EXP2F(sv[7])); \
    unsigned e4 = pkbf(EXP2F(sv[8]),  EXP2F(sv[9])); \
    unsigned e5 = pkbf(EXP2F(sv[10]), EXP2F(sv[11])); \
    unsigned e6 = pkbf(EXP2F(sv[12]), EXP2F(sv[13])); \
    unsigned e7 = pkbf(EXP2F(sv[14]), EXP2F(sv[15])); \
    auto r02 = __builtin_amdgcn_permlane32_swap(e0, e2, false, false); \
    auto r13 = __builtin_amdgcn_permlane32_swap(e1, e3, false, false); \
    auto r46 = __builtin_amdgcn_permlane32_swap(e4, e6, false, false); \
    auto r57 = __builtin_amdgcn_permlane32_swap(e5, e7, false, false); \
    f[0].u[0] = r02[0]; f[0].u[1] = r13[0]; \
    f[0].u[2] = r02[1]; f[0].u[3] = r13[1]; \
    f[1].u[0] = r46[0]; f[1].u[1] = r57[0]; \
    f[1].u[2] = r46[1]; f[1].u[3] = r57[1]; \
} while (0)
#else
// validated fallback (shfl_xor / ds_bpermute path)
#define REPACK(sv, f) do { \
    unsigned e0 = pkbf(EXP2F(sv[0]),  EXP2F(sv[1])); \
    unsigned e1 = pkbf(EXP2F(sv[2]),  EXP2F(sv[3])); \
    unsigned e2 = pkbf(EXP2F(sv[4]),  EXP2F(sv[5])); \
    unsigned e3 = pkbf(EXP2F(sv[6]),  EXP2F(sv[7])); \
    unsigned e4 = pkbf(EXP2F(sv[8]),  EXP2F(sv[9])); \
    unsigned e5 = pkbf(EXP2F(sv[10]), EXP2F(sv[11])); \
    unsigned e6 = pkbf(EXP2F(sv[12]), EXP2F(sv[13])); \
    unsigned e7 = pkbf(EXP2F(sv[14]), EXP2F(sv[15])); \
    unsigned q0 = __shfl_xor(e0, 32), q1 = __shfl_xor(e1, 32); \
    unsigned q2 = __shfl_xor(e2, 32), q3 = __shfl_xor(e3, 32); \
    unsigned q4 = __shfl_xor(e4, 32), q5 = __shfl_xor(e5, 32); \
    unsigned q6 = __shfl_xor(e6, 32), q7 = __shfl_xor(e7, 32); \
    f[0].u[0] = lh ? q2 : e0;  f[0].u[1] = lh ? q3 : e1; \
    f[0].u[2] = lh ? e2 : q0;  f[0].u[3] = lh ? e3 : q1; \
    f[1].u[0] = lh ? q6 : e4;  f[1].u[1] = lh ? q7 : e5; \
    f[1].u[2] = lh ? e6 : q4;  f[1].u[3] = lh ? e7 : q5; \
} while (0)
#endif

// ---------------------------------------------------------------------------
// K0: convert 4 weight matrices fp32->bf16. wall = [tw|pw|gw|Ww], 32768 each.
// theta weights pre-scaled by log2(e): scores land in exp2 domain.
// ---------------------------------------------------------------------------
__global__ __launch_bounds__(256) void k_cvtw(
    const float* __restrict__ tw, const float* __restrict__ pw,
    const float* __restrict__ gw, const float* __restrict__ Ww,
    u16* __restrict__ wall)
{
    int idx = (blockIdx.x * 256 + threadIdx.x) * 4;   // 0 .. 131071
    const float* s = (idx < 32768) ? tw
                   : (idx < 65536) ? pw
                   : (idx < 98304) ? gw : Ww;
    float sc = (idx < 32768) ? LOG2E : 1.0f;
    float4 v = *(const float4*)(s + (idx & 32767));
    us4 r = { f2bf(v.x * sc), f2bf(v.y * sc), f2bf(v.z * sc), f2bf(v.w * sc) };
    *(us4*)(wall + idx) = r;
}

// ---------------------------------------------------------------------------
// K1: MFMA projections (16x16 path, unchanged — validated).
//  tht/pht: [b][n][c] bf16 k-major; gg: [b][c][n] bf16 (k-major in j).
// ---------------------------------------------------------------------------
__global__ __launch_bounds__(512) void k_proj(
    const float* __restrict__ x, const u16* __restrict__ wall,
    const float* __restrict__ tb, const float* __restrict__ pb,
    const float* __restrict__ gbias,
    u16* __restrict__ tht, u16* __restrict__ pht, u16* __restrict__ gg)
{
    __shared__ u16 xs[64 * 264];    // x^T tile [n][c], pitch 264
    __shared__ u16 gbuf[128 * 68];  // g transpose bounce [o][n]
    const int tid = threadIdx.x;
    const int n0  = blockIdx.x * 64;
    const int b   = blockIdx.y;
    const int ln  = tid & 15, q = (tid >> 4) & 3, wid = tid >> 6;
    const int ow  = wid & 1, nw = wid >> 1;

    for (int p = 0; p < 8; ++p) {
        int id = p * 512 + tid;          // 4096 chunks: c(256) x n4(16)
        int c = id >> 4, n4 = (id & 15) * 4;
        float4 xv = *(const float4*)(x + ((size_t)b * CC + c) * NN + n0 + n4);
        xs[(n4 + 0) * 264 + c] = f2bf(xv.x);
        xs[(n4 + 1) * 264 + c] = f2bf(xv.y);
        xs[(n4 + 2) * 264 + c] = f2bf(xv.z);
        xs[(n4 + 3) * 264 + c] = f2bf(xv.w);
    }
    __syncthreads();

    short8 bfr[8];
    #pragma unroll
    for (int ks = 0; ks < 8; ++ks)
        bfr[ks] = *(const short8*)(&xs[(nw * 16 + ln) * 264 + ks * 32 + q * 8]);

    for (int pr = 0; pr < 3; ++pr) {
        const u16* wsrc = wall + pr * 32768;
        f32x4 acc[4];
        #pragma unroll
        for (int oo = 0; oo < 4; ++oo) acc[oo] = (f32x4){0.f, 0.f, 0.f, 0.f};
        for (int ks = 0; ks < 8; ++ks) {
            short8 a[4];
            #pragma unroll
            for (int oo = 0; oo < 4; ++oo)
                a[oo] = *(const short8*)(wsrc + (size_t)(ow*64 + oo*16 + ln) * 256 + ks*32 + q*8);
            #pragma unroll
            for (int oo = 0; oo < 4; ++oo)
                acc[oo] = MFMA16(a[oo], bfr[ks], acc[oo]);
        }
        const float* bias = (pr == 0) ? tb : (pr == 1 ? pb : gbias);
        const float bsc = (pr == 0) ? LOG2E : 1.0f;
        if (pr < 2) {
            u16* dst = (pr == 0) ? tht : pht;
            const int n = n0 + nw * 16 + ln;
            #pragma unroll
            for (int oo = 0; oo < 4; ++oo) {
                int o = ow * 64 + oo * 16 + q * 4;
                float4 bv = *(const float4*)(bias + o);
                f32x4 v = acc[oo];
                uint2 r = { pkbf(v.x + bv.x * bsc, v.y + bv.y * bsc),
                            pkbf(v.z + bv.z * bsc, v.w + bv.w * bsc) };
                *(uint2*)(dst + ((size_t)b * NN + n) * CHN + o) = r;
            }
        } else {
            const int nl = nw * 16 + ln;
            #pragma unroll
            for (int oo = 0; oo < 4; ++oo) {
                int o = ow * 64 + oo * 16 + q * 4;
                float4 bv = *(const float4*)(bias + o);
                f32x4 v = acc[oo];
                gbuf[(o + 0) * 68 + nl] = f2bf(v.x + bv.x);
                gbuf[(o + 1) * 68 + nl] = f2bf(v.y + bv.y);
                gbuf[(o + 2) * 68 + nl] = f2bf(v.z + bv.z);
                gbuf[(o + 3) * 68 + nl] = f2bf(v.w + bv.w);
            }
            __syncthreads();
            for (int p = 0; p < 4; ++p) {
                int id = p * 512 + tid;      // 2048 chunks: c(128) x n4(16)
                int c = id >> 4, n4 = (id & 15) * 4;
                us4 r = *(const us4*)(&gbuf[c * 68 + n4]);
                *(us4*)(gg + ((size_t)b * CHN + c) * NN + n0 + n4) = r;
            }
        }
    }
}

// ---------------------------------------------------------------------------
// K2: partial Z[b][j] += sum_i exp2(S2_ji), fp32 atomicAdd. 32x32x16 MFMA.
// R2 version exactly (validated; R9's direct-global variant regressed ~2x).
// ---------------------------------------------------------------------------
__global__ __launch_bounds__(512, 2) void k_rowsum(
    const u16* __restrict__ tht, const u16* __restrict__ pht,
    float* __restrict__ Z)
{
    __shared__ u16 ph_s[2][128 * 128];   // 2 x 32 KB [i][c]
    const int tid = threadIdx.x;
    const int j0  = blockIdx.x * 256;
    const int i00 = blockIdx.y * 1024;
    const int b   = blockIdx.z;
    const int l   = tid & 63, w = tid >> 6;
    const int lm  = l & 31, lh = l >> 5;
    const u16* thb = tht + (size_t)b * NN * CHN;
    const u16* phb = pht + (size_t)b * NN * CHN;

    short8 ar[8];
    #pragma unroll
    for (int ks = 0; ks < 8; ++ks)
        ar[ks] = *(const short8*)(thb + (size_t)(j0 + w*32 + lm) * CHN + ks*16 + lh*8);

    for (int p = 0; p < 4; ++p) {
        int id = p * 512 + tid;
        int row = id >> 4, u = id & 15;
        short8 v = *(const short8*)(phb + (size_t)(i00 + row) * CHN + u * 8);
        *(short8*)(&ph_s[0][sw128(row, u)]) = v;
    }

    float zp[16];
    #pragma unroll
    for (int r = 0; r < 16; ++r) zp[r] = 0.f;

    for (int is = 0; is < 8; ++is) {
        __syncthreads();
        if (is < 7) {
            for (int p = 0; p < 4; ++p) {
                int id = p * 512 + tid;
                int row = id >> 4, u = id & 15;
                short8 v = *(const short8*)(phb + (size_t)(i00 + (is+1)*128 + row) * CHN + u * 8);
                *(short8*)(&ph_s[(is + 1) & 1][sw128(row, u)]) = v;
            }
        }
        const u16* cur = ph_s[is & 1];

        #pragma unroll
        for (int ii = 0; ii < 4; ++ii) {
            f32x16 s;
            #pragma unroll
            for (int r = 0; r < 16; ++r) s[r] = 0.f;
            #pragma unroll
            for (int ks = 0; ks < 8; ++ks) {
                short8 bfrag = *(const short8*)(&cur[sw128(ii*32 + lm, ks*2 + lh)]);
                s = MFMA32(ar[ks], bfrag, s);
            }
            #pragma unroll
            for (int r = 0; r < 16; ++r) zp[r] += EXP2F(s[r]);
        }
    }

    float zr[16];
    #pragma unroll
    for (int r = 0; r < 16; ++r) {
        float v = zp[r];
        v += __shfl_xor(v, 1);
        v += __shfl_xor(v, 2);
        v += __shfl_xor(v, 4);
        v += __shfl_xor(v, 8);
        v += __shfl_xor(v, 16);
        zr[r] = v;
    }
    if (lm == 0) {
        #pragma unroll
        for (int r = 0; r < 16; ++r) {
            int j = j0 + w*32 + (r & 3) + 8*(r >> 2) + 4*lh;
            atomicAdd(&Z[(size_t)b * NN + j], zr[r]);
        }
    }
}

// ---------------------------------------------------------------------------
// K2b: g-prescale — gg[b][c][j] *= rcp(Z[b][j]). Folds the softmax
// normalization into g (algebraically identical to the old C-init = -log2 Z:
// out = sum_j (g/Z)*exp2(s2)). Removes 128 global L-loads + 16 C-init movs
// per wave from k_attn's hot loop. 8 MB r/w, memory-bound (~2 us).
// Overflow-safe: rowsum already computes raw exp2(s2) in f32 and passes;
// bf16 shares f32's exponent range.
// ---------------------------------------------------------------------------
__global__ __launch_bounds__(256) void k_gdiv(
    const float* __restrict__ Z, u16* __restrict__ gg)
{
    int q = blockIdx.x * 256 + threadIdx.x;      // 0 .. 524287 (x4 bf16 each)
    int b   = q >> 17;
    int rem = q & 131071;
    int c   = rem >> 10;
    int n4  = (rem & 1023) * 4;
    size_t base = ((size_t)b * CHN + c) * NN + n4;
    us4 g = *(const us4*)(gg + base);
    float4 z = *(const float4*)(Z + (size_t)b * NN + n4);
    us4 r = { f2bf(bf2f(g.x) * RCPF(z.x)), f2bf(bf2f(g.y) * RCPF(z.y)),
              f2bf(bf2f(g.z) * RCPF(z.z)), f2bf(bf2f(g.w) * RCPF(z.w)) };
    *(us4*)(gg + base) = r;
}

// ---------------------------------------------------------------------------
// K3 v10: fused attention — R2-EXACT structure (best measured: 50.7 us),
// minus the Lbuf C-init path (normalization now folded into gg by k_gdiv):
// sv starts at 0, E = raw exp2(s2). Per-wave hot loop loses 128 global
// float4 loads + 16 register inits. All else bit-identical to R2: 512 thr,
// 8 i-waves of i-32, pacc[4], phr[8], async gload_lds staging (pre-swizzled
// source + linear dest + sw128 reads), permlane REPACK, 1 barrier/step,
// 128 KB LDS, grid (16,4,B).
// D-layout (m74/m101): col=lane&31, row=(r&3)+8*(r>>2)+4*(lane>>5).
// ---------------------------------------------------------------------------
__global__ __launch_bounds__(512, 2) void k_attn(
    const u16* __restrict__ tht, const u16* __restrict__ pht,
    const u16* __restrict__ gg, u16* __restrict__ innerT)
{
    __shared__ u16 th_s[2][128 * 128];   // [j][c] per step, dbuf
    __shared__ u16 g_s [2][128 * 128];   // [c][j] per step, dbuf
    const int tid = threadIdx.x;
    const int i0  = blockIdx.x * 256;
    const int jq  = blockIdx.y;
    const int b   = blockIdx.z;
    const int w   = tid >> 6;
    const int lm  = tid & 31, lh = (tid >> 5) & 1;

    const u16*  thb = tht + (size_t)b * NN * CHN;
    const u16*  ggb = gg  + (size_t)b * CHN * NN;

    int offT[4], offG[4];
    #pragma unroll
    for (int p = 0; p < 4; ++p) {
        int row = p * 32 + (tid >> 4);
        int u   = (tid & 15) ^ (row & 7);
        offT[p] = row * CHN + u * 8;
        offG[p] = row * NN  + u * 8;
    }

    short8 phr[8];
    #pragma unroll
    for (int ks = 0; ks < 8; ++ks)
        phr[ks] = *(const short8*)(pht + ((size_t)b * NN + i0 + w*32 + lm) * CHN + ks*16 + lh*8);

    #pragma unroll
    for (int p = 0; p < 4; ++p) {
        gload16(thb + (size_t)(jq * 1024) * CHN + offT[p], &th_s[0][0] + p*4096 + (w << 9));
        gload16(ggb + jq * 1024 + offG[p],                 &g_s [0][0] + p*4096 + (w << 9));
    }
    __syncthreads();

    f32x16 pacc[4];
    #pragma unroll
    for (int ct = 0; ct < 4; ++ct)
        #pragma unroll
        for (int r = 0; r < 16; ++r) pacc[ct][r] = 0.f;

    for (int s = 0; s < 8; ++s) {
        const int j0s = jq * 1024 + s * 128;
        const u16* thc = th_s[s & 1];
        const u16* gc  = g_s [s & 1];

        if (s < 7) {
            const int nb = (s + 1) & 1;
            #pragma unroll
            for (int p = 0; p < 4; ++p) {
                gload16(thb + (size_t)(j0s + 128) * CHN + offT[p], &th_s[nb][0] + p*4096 + (w << 9));
                gload16(ggb + (j0s + 128) + offG[p],               &g_s [nb][0] + p*4096 + (w << 9));
            }
        }

        #pragma unroll
        for (int jj = 0; jj < 4; ++jj) {
            f32x16 sv;
            #pragma unroll
            for (int r = 0; r < 16; ++r) sv[r] = 0.f;
            #pragma unroll
            for (int ks = 0; ks < 8; ++ks) {
                short8 a = *(const short8*)(&thc[sw128(jj*32 + lm, ks*2 + lh)]);
                sv = MFMA32(a, phr[ks], sv);
            }
            bfrag f[2];
            REPACK(sv, f);
            #pragma unroll
            for (int h = 0; h < 2; ++h) {
                #pragma unroll
                for (int ct = 0; ct < 4; ++ct) {
                    short8 ag = *(const short8*)(&gc[sw128(ct*32 + lm, jj*4 + h*2 + lh)]);
                    pacc[ct] = MFMA32(ag, f[h].v, pacc[ct]);
                }
            }
        }
        __syncthreads();
    }

    u16* dst = innerT + ((size_t)jq * BB + b) * (size_t)NN * CHN;
    const int i = i0 + w*32 + lm;
    #pragma unroll
    for (int ct = 0; ct < 4; ++ct) {
        #pragma unroll
        for (int rq = 0; rq < 4; ++rq) {
            const int c0 = ct*32 + rq*8 + lh*4;
            uint2 r = { pkbf(pacc[ct][rq*4+0], pacc[ct][rq*4+1]),
                        pkbf(pacc[ct][rq*4+2], pacc[ct][rq*4+3]) };
            *(uint2*)(dst + (size_t)i * CHN + c0) = r;
        }
    }
}

// ---------------------------------------------------------------------------
// K4: out = Wb + x + Ww.(sum_q innerT_q) — 4 j-slabs, R2-exact (validated).
// ---------------------------------------------------------------------------
__global__ __launch_bounds__(512, 2) void k_final(
    const u16* __restrict__ innerT, const float* __restrict__ x,
    const u16* __restrict__ Wwbf, const float* __restrict__ Wb,
    float* __restrict__ out)
{
    __shared__ u16 w_s[256 * 128];   // 64 KB [o][c]
    __shared__ u16 a_s[64 * 128];    // 16 KB [n][c]
    const int tid = threadIdx.x;
    const int n0  = blockIdx.x * 64;
    const int b   = blockIdx.y;
    const int l   = tid & 63, w = tid >> 6;
    const int lm  = l & 31, lh = l >> 5;

    for (int p = 0; p < 8; ++p) {
        int id = p * 512 + tid;
        int row = id >> 4, u = id & 15;
        *(short8*)(&w_s[sw128(row, u)]) = *(const short8*)(Wwbf + (size_t)row * CHN + u * 8);
    }
    __syncthreads();

    short8 aw[8];
    #pragma unroll
    for (int ks = 0; ks < 8; ++ks)
        aw[ks] = *(const short8*)(&w_s[sw128(w*32 + lm, ks*2 + lh)]);

    f32x16 acc[2];
    #pragma unroll
    for (int nt = 0; nt < 2; ++nt)
        #pragma unroll
        for (int r = 0; r < 16; ++r) acc[nt][r] = 0.f;

    for (int jq = 0; jq < 4; ++jq) {
        __syncthreads();
        for (int p = 0; p < 2; ++p) {
            int id = p * 512 + tid;
            int row = id >> 4, u = id & 15;
            *(short8*)(&a_s[sw128(row, u)]) =
                *(const short8*)(innerT + (((size_t)jq * BB + b) * NN + n0 + row) * CHN + u * 8);
        }
        __syncthreads();
        #pragma unroll
        for (int ks = 0; ks < 8; ++ks) {
            short8 bn[2];
            #pragma unroll
            for (int nt = 0; nt < 2; ++nt)
                bn[nt] = *(const short8*)(&a_s[sw128(nt*32 + lm, ks*2 + lh)]);
            acc[0] = MFMA32(aw[ks], bn[0], acc[0]);
            acc[1] = MFMA32(aw[ks], bn[1], acc[1]);
        }
    }

    #pragma unroll
    for (int nt = 0; nt < 2; ++nt) {
        const int n = n0 + nt*32 + lm;
        #pragma unroll
        for (int r = 0; r < 16; ++r) {
            const int o = w*32 + (r & 3) + 8*(r >> 2) + 4*lh;
            const size_t idx = ((size_t)b * CC + o) * NN + n;
            out[idx] = acc[nt][r] + Wb[o] + x[idx];
        }
    }
}

// ---------------------------------------------------------------------------
extern "C" void kernel_launch(void* const* d_in, const int* in_sizes, int n_in,
                              void* d_out, int out_size, void* d_ws, size_t ws_size,
                              hipStream_t stream)
{
    const float* x  = (const float*)d_in[0];
    const float* tw = (const float*)d_in[1];
    const float* tb = (const float*)d_in[2];
    const float* pw = (const float*)d_in[3];
    const float* pb = (const float*)d_in[4];
    const float* gw = (const float*)d_in[5];
    const float* gb = (const float*)d_in[6];
    const float* Ww = (const float*)d_in[7];
    const float* Wb = (const float*)d_in[8];
    float* out = (float*)d_out;

    // Workspace (~29 MB): tht|pht|gg (4MB ea bf16) | wall (256KB) |
    // Z (64KB, memset 0) | innerT 4 j-slabs x 4MB bf16.
    char* p = (char*)d_ws;
    const size_t proj_u16 = (size_t)BB * NN * CHN;   // 2,097,152
    u16*   tht    = (u16*)p;   p += proj_u16 * 2;
    u16*   pht    = (u16*)p;   p += proj_u16 * 2;
    u16*   gg     = (u16*)p;   p += proj_u16 * 2;
    u16*   wall   = (u16*)p;   p += (size_t)131072 * 2;
    float* Z      = (float*)p; p += (size_t)BB * NN * 4;
    u16*   innerT = (u16*)p;

    hipMemsetAsync(Z, 0, (size_t)BB * NN * sizeof(float), stream);
    k_cvtw  <<<128, 256, 0, stream>>>(tw, pw, gw, Ww, wall);
    k_proj  <<<dim3(64, BB), 512, 0, stream>>>(x, wall, tb, pb, gb, tht, pht, gg);
    k_rowsum<<<dim3(16, 4, BB), 512, 0, stream>>>(tht, pht, Z);
    k_gdiv  <<<2048, 256, 0, stream>>>(Z, gg);
    k_attn  <<<dim3(16, 4, BB), 512, 0, stream>>>(tht, pht, gg, innerT);
    k_final <<<dim3(64, BB), 512, 0, stream>>>(innerT, x, wall + 98304, Wb, out);
}